// Round 5
// baseline (404.321 us; speedup 1.0000x reference)
//
#include <hip/hip_runtime.h>
#include <math.h>

#define IN_DIM 256
#define HID 64
#define OUT_DIM 40
#define EPS_RES 0.3f
#define SCAN_BLK 256

__device__ __forceinline__ float tanh_fast(float u) {
    // tanh(u) = 1 - 2/(exp(2u)+1); exact limits at +-inf
    float t = __expf(2.0f * u);
    return 1.0f - 2.0f / (t + 1.0f);
}

// ---------------------------------------------------------------- degree
__global__ void k_deg(const int* __restrict__ dst, int* __restrict__ deg, int E) {
    int i = blockIdx.x * blockDim.x + threadIdx.x;
    if (i < E) atomicAdd(&deg[dst[i]], 1);
}

__global__ void k_dinv(const int* __restrict__ deg, float* __restrict__ dinv, int N) {
    int i = blockIdx.x * blockDim.x + threadIdx.x;
    if (i < N) dinv[i] = rsqrtf(fmaxf((float)deg[i], 1.0f));
}

// ------------------------------------------------------- CSR build: scan
__global__ void k_scan_block(const int* __restrict__ deg, int* __restrict__ incl,
                             int* __restrict__ bsum, int N) {
    __shared__ int sm[SCAN_BLK];
    int tid = threadIdx.x;
    int i = blockIdx.x * SCAN_BLK + tid;
    sm[tid] = (i < N) ? deg[i] : 0;
    __syncthreads();
    for (int off = 1; off < SCAN_BLK; off <<= 1) {
        int t = (tid >= off) ? sm[tid - off] : 0;
        __syncthreads();
        sm[tid] += t;
        __syncthreads();
    }
    if (i < N) incl[i] = sm[tid];
    if (tid == SCAN_BLK - 1) bsum[blockIdx.x] = sm[tid];
}

// NB <= 256
__global__ void k_scan_tops(const int* __restrict__ bsum, int* __restrict__ boff, int NB) {
    __shared__ int sm[SCAN_BLK];
    int tid = threadIdx.x;
    int v = (tid < NB) ? bsum[tid] : 0;
    sm[tid] = v;
    __syncthreads();
    for (int off = 1; off < SCAN_BLK; off <<= 1) {
        int t = (tid >= off) ? sm[tid - off] : 0;
        __syncthreads();
        sm[tid] += t;
        __syncthreads();
    }
    if (tid < NB) boff[tid] = sm[tid] - v;  // exclusive block offsets
}

__global__ void k_scan_add(const int* __restrict__ incl, const int* __restrict__ boff,
                           const int* __restrict__ deg, int* __restrict__ rowp,
                           int* __restrict__ cursor, int N) {
    int i = blockIdx.x * SCAN_BLK + threadIdx.x;
    if (i >= N) return;
    int inc = incl[i] + boff[blockIdx.x];
    rowp[i + 1] = inc;
    cursor[i] = inc - deg[i];
    if (i == 0) rowp[0] = 0;
}

__global__ void k_place(const int* __restrict__ src, const int* __restrict__ dst,
                        int* __restrict__ cursor, int* __restrict__ ssrc, int E) {
    int i = blockIdx.x * blockDim.x + threadIdx.x;
    if (i >= E) return;
    int t = dst[i];
    int p = atomicAdd(&cursor[t], 1);
    ssrc[p] = src[i];
}

// --------------------- x0 = relu(h @ W1^T + b1), fused gate proj for layer 1
// lane = output column (HID=64 = wave). W1 staged whole in LDS (64KB) as
// w4[kb][col^(kb&7)] float4 slots: stage-read coalesced, compute-read is a
// contiguous 1KB/wave ds_read_b128 (conflict-free, offset:kb*1024 folds).
// h rows are WAVE-UNIFORM (blockIdx + readfirstlane(wv) + unrolled r) ->
// compiler emits s_load; lgkm queue holds only SMEM in the hot loop, so the
// h stream pipelines. Inner body per kb per 8-row chunk:
//   1 ds_read_b128 (12cyc) + 32 v_fmac (SGPR h-operand, 64cyc) -> VALU-bound.
// Epilogue: relu+bias, coalesced 256B row stores, gate partials via shfl_xor
// (lane=col makes the gate dot a natural wave reduce).
__global__ __launch_bounds__(256) void k_gemm1(
    const float* __restrict__ h, const float* __restrict__ w,
    const float* __restrict__ b, const float* __restrict__ gw,
    float* __restrict__ out, float* __restrict__ gpa, float* __restrict__ gpb,
    int N) {
    __shared__ float4 wlds[64 * 64];   // 64KB: slot = kb*64 + (col ^ (kb&7))

    int tid = threadIdx.x;
    // ---- stage W1 (coalesced global read; one-time swizzled LDS write)
    const float4* wf4 = (const float4*)w;   // w[col][k]: float4 idx = col*64+kb
#pragma unroll
    for (int i = 0; i < 16; ++i) {
        int idx = i * 256 + tid;             // 0..4095
        int col = idx >> 6, kb = idx & 63;
        wlds[(kb << 6) | (col ^ (kb & 7))] = wf4[idx];
    }
    __syncthreads();

    int lane = tid & 63;
    int wv = __builtin_amdgcn_readfirstlane(tid >> 6);
    int row0 = blockIdx.x * 64 + wv * 16;    // this wave's 16 rows

    float bias = b[lane];
    float gwa = gw[lane];
    float gwb = gw[HID + lane];

    float acc[16];
#pragma unroll
    for (int r = 0; r < 16; ++r) acc[r] = 0.f;

    // row pointers (wave-uniform, clamped)
#define HROW(r) (const float4*)(h + (size_t)((row0 + (r)) < N ? (row0 + (r)) : (N - 1)) * IN_DIM)
    {   // rows 0..7
        const float4 *h0 = HROW(0), *h1 = HROW(1), *h2 = HROW(2), *h3 = HROW(3),
                     *h4 = HROW(4), *h5 = HROW(5), *h6 = HROW(6), *h7 = HROW(7);
#pragma unroll 4
        for (int kb = 0; kb < 64; ++kb) {
            float4 w4 = wlds[(kb << 6) | (lane ^ (kb & 7))];
#define FMA4(A, HV) { float4 hv = (HV); \
            A = fmaf(hv.x, w4.x, A); A = fmaf(hv.y, w4.y, A); \
            A = fmaf(hv.z, w4.z, A); A = fmaf(hv.w, w4.w, A); }
            FMA4(acc[0], h0[kb]); FMA4(acc[1], h1[kb]);
            FMA4(acc[2], h2[kb]); FMA4(acc[3], h3[kb]);
            FMA4(acc[4], h4[kb]); FMA4(acc[5], h5[kb]);
            FMA4(acc[6], h6[kb]); FMA4(acc[7], h7[kb]);
        }
    }
    {   // rows 8..15
        const float4 *h0 = HROW(8), *h1 = HROW(9), *h2 = HROW(10), *h3 = HROW(11),
                     *h4 = HROW(12), *h5 = HROW(13), *h6 = HROW(14), *h7 = HROW(15);
#pragma unroll 4
        for (int kb = 0; kb < 64; ++kb) {
            float4 w4 = wlds[(kb << 6) | (lane ^ (kb & 7))];
            FMA4(acc[8], h0[kb]);  FMA4(acc[9], h1[kb]);
            FMA4(acc[10], h2[kb]); FMA4(acc[11], h3[kb]);
            FMA4(acc[12], h4[kb]); FMA4(acc[13], h5[kb]);
            FMA4(acc[14], h6[kb]); FMA4(acc[15], h7[kb]);
        }
    }
#undef FMA4
#undef HROW

    // ---- epilogue: relu+bias, row stores, gate partials via wave reduce
#pragma unroll
    for (int r = 0; r < 16; ++r) {
        int rr = row0 + r;
        float v = fmaxf(acc[r] + bias, 0.f);
        if (rr < N) out[(size_t)rr * HID + lane] = v;
        float pa = v * gwa;
        float pb = v * gwb;
#pragma unroll
        for (int m = 32; m; m >>= 1) {
            pa += __shfl_xor(pa, m);
            pb += __shfl_xor(pb, m);
        }
        if (lane == 0 && rr < N) {
            gpa[rr] = pa;
            gpb[rr] = pb;
        }
    }
}

// ---- gather: z[t] = EPS*raw[t] + sum_e tanh(ga[t]+gb[s]+bias)*d[t]*d[s]*x[s]
// one wave per node, lane = hid dim; edge gate computed inline (scalar loads,
// wave-redundant VALU hidden under x-row gather latency). Epilogue computes
// next layer's gate projections via wave shfl reduce.
__global__ __launch_bounds__(256) void k_gather(
    const int* __restrict__ rowp, const int* __restrict__ ssrc,
    const float* __restrict__ gpa, const float* __restrict__ gpb,
    const float* __restrict__ dinv, const float* __restrict__ gbias,
    const float* __restrict__ x, const float* __restrict__ raw,
    float* __restrict__ z,
    const float* __restrict__ gw_next, float* __restrict__ gpa_next,
    float* __restrict__ gpb_next, int N) {
    int lane = threadIdx.x & 63;
    int wv = __builtin_amdgcn_readfirstlane(threadIdx.x >> 6);
    int t = blockIdx.x * 4 + wv;
    if (t >= N) return;

    float at = gpa[t] + gbias[0];
    float dt = dinv[t];
    float acc = EPS_RES * raw[((size_t)t << 6) + lane];
    int k = rowp[t];
    int end = rowp[t + 1];
    for (; k + 2 <= end; k += 2) {
        int s0 = ssrc[k], s1 = ssrc[k + 1];
        float e0 = tanh_fast(at + gpb[s0]) * dt * dinv[s0];
        float e1 = tanh_fast(at + gpb[s1]) * dt * dinv[s1];
        acc = fmaf(e0, x[((size_t)s0 << 6) + lane], acc);
        acc = fmaf(e1, x[((size_t)s1 << 6) + lane], acc);
    }
    if (k < end) {
        int s0 = ssrc[k];
        float e0 = tanh_fast(at + gpb[s0]) * dt * dinv[s0];
        acc = fmaf(e0, x[((size_t)s0 << 6) + lane], acc);
    }
    z[((size_t)t << 6) + lane] = acc;

    if (gw_next) {
        float pa = acc * gw_next[lane];
        float pb = acc * gw_next[HID + lane];
#pragma unroll
        for (int m = 32; m; m >>= 1) {
            pa += __shfl_xor(pa, m);
            pb += __shfl_xor(pb, m);
        }
        if (lane == 0) {
            gpa_next[t] = pa;
            gpb_next[t] = pb;
        }
    }
}

// ------------------------------------- logits = x @ W2^T + b2, log_softmax
__global__ __launch_bounds__(256) void k_head(
    const float* __restrict__ x, const float* __restrict__ w2,
    const float* __restrict__ b2, float* __restrict__ out, int N) {
    int n = blockIdx.x * 256 + threadIdx.x;
    if (n >= N) return;
    const float4* xr = (const float4*)(x + (size_t)n * HID);
    float acc[OUT_DIM];
#pragma unroll
    for (int j = 0; j < OUT_DIM; ++j) acc[j] = b2[j];
#pragma unroll 2
    for (int kb = 0; kb < HID / 4; ++kb) {
        float4 v = xr[kb];
#pragma unroll
        for (int j = 0; j < OUT_DIM; ++j) {
            const float* wr = w2 + (size_t)j * HID + kb * 4;
            acc[j] = fmaf(v.x, wr[0], acc[j]);
            acc[j] = fmaf(v.y, wr[1], acc[j]);
            acc[j] = fmaf(v.z, wr[2], acc[j]);
            acc[j] = fmaf(v.w, wr[3], acc[j]);
        }
    }
    float m = acc[0];
#pragma unroll
    for (int j = 1; j < OUT_DIM; ++j) m = fmaxf(m, acc[j]);
    float ssum = 0.f;
#pragma unroll
    for (int j = 0; j < OUT_DIM; ++j) ssum += expf(acc[j] - m);
    float lse = m + logf(ssum);
    float* o = out + (size_t)n * OUT_DIM;
#pragma unroll
    for (int j = 0; j < OUT_DIM; ++j) o[j] = acc[j] - lse;
}

// ----------------------------------------------------------------- launcher
extern "C" void kernel_launch(void* const* d_in, const int* in_sizes, int n_in,
                              void* d_out, int out_size, void* d_ws, size_t ws_size,
                              hipStream_t stream) {
    const float* h    = (const float*)d_in[0];
    const int*   src  = (const int*)d_in[1];
    const int*   dst  = (const int*)d_in[2];
    const float* t1_w = (const float*)d_in[3];
    const float* t1_b = (const float*)d_in[4];
    const float* gw1  = (const float*)d_in[5];
    const float* gb1  = (const float*)d_in[6];
    const float* gw2  = (const float*)d_in[7];
    const float* gb2  = (const float*)d_in[8];
    const float* t2_w = (const float*)d_in[9];
    const float* t2_b = (const float*)d_in[10];
    float* out = (float*)d_out;

    const int N = in_sizes[0] / IN_DIM;
    const int E = in_sizes[1];
    const int NB = (N + SCAN_BLK - 1) / SCAN_BLK;

    // workspace layout
    float* ws   = (float*)d_ws;
    float* raw  = ws;                          // N*64
    float* xA   = raw + (size_t)N * HID;       // N*64
    float* xB   = xA + (size_t)N * HID;        // N*64
    float* dinv = xB + (size_t)N * HID;        // N
    float* gpa1 = dinv + N;                    // N
    float* gpb1 = gpa1 + N;                    // N
    float* gpa2 = gpb1 + N;                    // N
    float* gpb2 = gpa2 + N;                    // N
    int* deg    = (int*)(gpb2 + N);            // N
    int* incl   = deg + N;                     // N
    int* rowp   = incl + N;                    // N+1
    int* cursor = rowp + N + 1;                // N
    int* bsum   = cursor + N;                  // NB
    int* boff   = bsum + NB;                   // NB
    int* ssrc   = boff + NB;                   // E

    const int TB = 256;
    hipMemsetAsync(deg, 0, (size_t)N * sizeof(int), stream);
    k_deg<<<(E + TB - 1) / TB, TB, 0, stream>>>(dst, deg, E);
    k_dinv<<<NB, TB, 0, stream>>>(deg, dinv, N);
    k_scan_block<<<NB, TB, 0, stream>>>(deg, incl, bsum, N);
    k_scan_tops<<<1, TB, 0, stream>>>(bsum, boff, NB);
    k_scan_add<<<NB, TB, 0, stream>>>(incl, boff, deg, rowp, cursor, N);
    k_place<<<(E + TB - 1) / TB, TB, 0, stream>>>(src, dst, cursor, ssrc, E);

    // x0 = relu(h W1^T + b1), plus layer-1 gate projections
    k_gemm1<<<(N + 63) / 64, TB, 0, stream>>>(h, t1_w, t1_b, gw1, raw, gpa1, gpb1, N);

    // layer 1: raw -> xA (epilogue computes layer-2 gate projections)
    k_gather<<<(N + 3) / 4, TB, 0, stream>>>(rowp, ssrc, gpa1, gpb1, dinv, gb1,
                                             raw, raw, xA, gw2, gpa2, gpb2, N);

    // layer 2: xA -> xB
    k_gather<<<(N + 3) / 4, TB, 0, stream>>>(rowp, ssrc, gpa2, gpb2, dinv, gb2,
                                             xA, raw, xB, nullptr, nullptr, nullptr, N);

    k_head<<<(N + TB - 1) / TB, TB, 0, stream>>>(xB, t2_w, t2_b, out, N);
}

// Round 6
// 260.693 us; speedup vs baseline: 1.5509x; 1.5509x over previous
//
#include <hip/hip_runtime.h>
#include <hip/hip_bf16.h>
#include <math.h>

#define IN_DIM 256
#define HID 64
#define OUT_DIM 40
#define EPS_RES 0.3f
#define SCAN_BLK 256

typedef __attribute__((ext_vector_type(8))) short short8v;   // bf16x8 frag (4 VGPR)
typedef __attribute__((ext_vector_type(4))) float f32x4;     // MFMA C/D frag

__device__ __forceinline__ float tanh_fast(float u) {
    float t = __expf(2.0f * u);
    return 1.0f - 2.0f / (t + 1.0f);
}

__device__ __forceinline__ short f2bf(float f) {
    __hip_bfloat16 b = __float2bfloat16(f);
    return __builtin_bit_cast(short, b);
}

// ---------------------------------------------------------------- degree
__global__ void k_deg(const int* __restrict__ dst, int* __restrict__ deg, int E) {
    int i = blockIdx.x * blockDim.x + threadIdx.x;
    if (i < E) atomicAdd(&deg[dst[i]], 1);
}

__global__ void k_dinv(const int* __restrict__ deg, float* __restrict__ dinv, int N) {
    int i = blockIdx.x * blockDim.x + threadIdx.x;
    if (i < N) dinv[i] = rsqrtf(fmaxf((float)deg[i], 1.0f));
}

// ------------------------------------------------------- CSR build: scan
__global__ void k_scan_block(const int* __restrict__ deg, int* __restrict__ incl,
                             int* __restrict__ bsum, int N) {
    __shared__ int sm[SCAN_BLK];
    int tid = threadIdx.x;
    int i = blockIdx.x * SCAN_BLK + tid;
    sm[tid] = (i < N) ? deg[i] : 0;
    __syncthreads();
    for (int off = 1; off < SCAN_BLK; off <<= 1) {
        int t = (tid >= off) ? sm[tid - off] : 0;
        __syncthreads();
        sm[tid] += t;
        __syncthreads();
    }
    if (i < N) incl[i] = sm[tid];
    if (tid == SCAN_BLK - 1) bsum[blockIdx.x] = sm[tid];
}

// NB <= 256
__global__ void k_scan_tops(const int* __restrict__ bsum, int* __restrict__ boff, int NB) {
    __shared__ int sm[SCAN_BLK];
    int tid = threadIdx.x;
    int v = (tid < NB) ? bsum[tid] : 0;
    sm[tid] = v;
    __syncthreads();
    for (int off = 1; off < SCAN_BLK; off <<= 1) {
        int t = (tid >= off) ? sm[tid - off] : 0;
        __syncthreads();
        sm[tid] += t;
        __syncthreads();
    }
    if (tid < NB) boff[tid] = sm[tid] - v;  // exclusive block offsets
}

__global__ void k_scan_add(const int* __restrict__ incl, const int* __restrict__ boff,
                           const int* __restrict__ deg, int* __restrict__ rowp,
                           int* __restrict__ cursor, int N) {
    int i = blockIdx.x * SCAN_BLK + threadIdx.x;
    if (i >= N) return;
    int inc = incl[i] + boff[blockIdx.x];
    rowp[i + 1] = inc;
    cursor[i] = inc - deg[i];
    if (i == 0) rowp[0] = 0;
}

__global__ void k_place(const int* __restrict__ src, const int* __restrict__ dst,
                        int* __restrict__ cursor, int* __restrict__ ssrc, int E) {
    int i = blockIdx.x * blockDim.x + threadIdx.x;
    if (i >= E) return;
    int t = dst[i];
    int p = atomicAdd(&cursor[t], 1);
    ssrc[p] = src[i];
}

// ------------------------------------------------ W1 f32 -> bf16 (one-time)
__global__ void k_wconv(const float* __restrict__ w, short* __restrict__ wpre, int n) {
    int i = blockIdx.x * blockDim.x + threadIdx.x;
    if (i < n) wpre[i] = f2bf(w[i]);
}

// --------------------- x0 = relu(h @ W1^T + b1) via MFMA bf16, fused gate proj
// Block = 4 waves; wave wv owns rows [blk*64+wv*16, +16). Per K-step (K=32):
//   A-frag straight from global h: lane -> row=(l&15), k=(l>>4)*8 (+0..7):
//   two dwordx4 = 16 full 128B lines per instr (zero waste), cvt f32->bf16.
//   B-frags (4 n-tiles) from pre-converted bf16 W1 (L2-resident, 16B/lane).
// C/D layout (m89): col = lane&15, row = (lane>>4)*4 + reg.
// Epilogue: bias+relu, coalesced stores, gate partials via 16-lane shfl_xor.
__global__ __launch_bounds__(256) void k_gemm1(
    const float* __restrict__ h, const short* __restrict__ wpre,
    const float* __restrict__ b, const float* __restrict__ gw,
    float* __restrict__ out, float* __restrict__ gpa, float* __restrict__ gpb,
    int N) {
    int tid = threadIdx.x;
    int lane = tid & 63;
    int l15 = lane & 15, lhi = lane >> 4;
    int wv = __builtin_amdgcn_readfirstlane(tid >> 6);
    int base = blockIdx.x * 64 + wv * 16;          // wave's row-tile base

    int ra = base + l15;                           // A-load row (per lane)
    if (ra >= N) ra = N - 1;
    const float* arow = h + (size_t)ra * IN_DIM + lhi * 8;

    f32x4 acc[4] = {{0.f,0.f,0.f,0.f},{0.f,0.f,0.f,0.f},
                    {0.f,0.f,0.f,0.f},{0.f,0.f,0.f,0.f}};

#pragma unroll
    for (int ks = 0; ks < 8; ++ks) {
        const float4* ap = (const float4*)(arow + ks * 32);
        float4 a0 = ap[0], a1 = ap[1];
        short8v af;
        af[0] = f2bf(a0.x); af[1] = f2bf(a0.y);
        af[2] = f2bf(a0.z); af[3] = f2bf(a0.w);
        af[4] = f2bf(a1.x); af[5] = f2bf(a1.y);
        af[6] = f2bf(a1.z); af[7] = f2bf(a1.w);

        const short* wk = wpre + (size_t)l15 * IN_DIM + ks * 32 + lhi * 8;
#pragma unroll
        for (int t = 0; t < 4; ++t) {
            short8v bf = *(const short8v*)(wk + t * 16 * IN_DIM);
            acc[t] = __builtin_amdgcn_mfma_f32_16x16x32_bf16(af, bf, acc[t], 0, 0, 0);
        }
    }

    // ---- epilogue: bias+relu, stores, gate partials (D: col=l15, row=lhi*4+r)
#pragma unroll
    for (int r = 0; r < 4; ++r) {
        int grow = base + lhi * 4 + r;
        float vals[4];
        float pa = 0.f, pb = 0.f;
#pragma unroll
        for (int t = 0; t < 4; ++t) {
            int col = t * 16 + l15;
            float v = fmaxf(acc[t][r] + b[col], 0.f);
            vals[t] = v;
            pa = fmaf(v, gw[col], pa);
            pb = fmaf(v, gw[HID + col], pb);
        }
        if (grow < N) {
            float* o = out + (size_t)grow * HID;
#pragma unroll
            for (int t = 0; t < 4; ++t) o[t * 16 + l15] = vals[t];
        }
        // reduce pa/pb across the 16 lanes of this lhi-group
#pragma unroll
        for (int m = 1; m < 16; m <<= 1) {
            pa += __shfl_xor(pa, m);
            pb += __shfl_xor(pb, m);
        }
        if (l15 == 0 && grow < N) {
            gpa[grow] = pa;
            gpb[grow] = pb;
        }
    }
}

// ---- gather: z[t] = EPS*raw[t] + sum_e tanh(ga[t]+gb[s]+bias)*d[t]*d[s]*x[s]
// one wave per node, lane = hid dim; 4-edge unroll = 4 independent load chains
// in flight. Epilogue computes next layer's gate projections via shfl reduce.
__global__ __launch_bounds__(256) void k_gather(
    const int* __restrict__ rowp, const int* __restrict__ ssrc,
    const float* __restrict__ gpa, const float* __restrict__ gpb,
    const float* __restrict__ dinv, const float* __restrict__ gbias,
    const float* __restrict__ x, const float* __restrict__ raw,
    float* __restrict__ z,
    const float* __restrict__ gw_next, float* __restrict__ gpa_next,
    float* __restrict__ gpb_next, int N) {
    int lane = threadIdx.x & 63;
    int wv = __builtin_amdgcn_readfirstlane(threadIdx.x >> 6);
    int t = blockIdx.x * 4 + wv;
    if (t >= N) return;

    float at = gpa[t] + gbias[0];
    float dt = dinv[t];
    float acc = EPS_RES * raw[((size_t)t << 6) + lane];
    int k = rowp[t];
    int end = rowp[t + 1];
    for (; k + 4 <= end; k += 4) {
        int s0 = ssrc[k], s1 = ssrc[k + 1], s2 = ssrc[k + 2], s3 = ssrc[k + 3];
        float p0 = gpb[s0], p1 = gpb[s1], p2 = gpb[s2], p3 = gpb[s3];
        float q0 = dinv[s0], q1 = dinv[s1], q2 = dinv[s2], q3 = dinv[s3];
        float x0 = x[((size_t)s0 << 6) + lane];
        float x1 = x[((size_t)s1 << 6) + lane];
        float x2 = x[((size_t)s2 << 6) + lane];
        float x3 = x[((size_t)s3 << 6) + lane];
        acc = fmaf(tanh_fast(at + p0) * dt * q0, x0, acc);
        acc = fmaf(tanh_fast(at + p1) * dt * q1, x1, acc);
        acc = fmaf(tanh_fast(at + p2) * dt * q2, x2, acc);
        acc = fmaf(tanh_fast(at + p3) * dt * q3, x3, acc);
    }
    for (; k < end; ++k) {
        int s0 = ssrc[k];
        float e0 = tanh_fast(at + gpb[s0]) * dt * dinv[s0];
        acc = fmaf(e0, x[((size_t)s0 << 6) + lane], acc);
    }
    z[((size_t)t << 6) + lane] = acc;

    if (gw_next) {
        float pa = acc * gw_next[lane];
        float pb = acc * gw_next[HID + lane];
#pragma unroll
        for (int m = 32; m; m >>= 1) {
            pa += __shfl_xor(pa, m);
            pb += __shfl_xor(pb, m);
        }
        if (lane == 0) {
            gpa_next[t] = pa;
            gpb_next[t] = pb;
        }
    }
}

// ------------------------------------- logits = x @ W2^T + b2, log_softmax
__global__ __launch_bounds__(256) void k_head(
    const float* __restrict__ x, const float* __restrict__ w2,
    const float* __restrict__ b2, float* __restrict__ out, int N) {
    int n = blockIdx.x * 256 + threadIdx.x;
    if (n >= N) return;
    const float4* xr = (const float4*)(x + (size_t)n * HID);
    float acc[OUT_DIM];
#pragma unroll
    for (int j = 0; j < OUT_DIM; ++j) acc[j] = b2[j];
#pragma unroll 2
    for (int kb = 0; kb < HID / 4; ++kb) {
        float4 v = xr[kb];
#pragma unroll
        for (int j = 0; j < OUT_DIM; ++j) {
            const float* wr = w2 + (size_t)j * HID + kb * 4;
            acc[j] = fmaf(v.x, wr[0], acc[j]);
            acc[j] = fmaf(v.y, wr[1], acc[j]);
            acc[j] = fmaf(v.z, wr[2], acc[j]);
            acc[j] = fmaf(v.w, wr[3], acc[j]);
        }
    }
    float m = acc[0];
#pragma unroll
    for (int j = 1; j < OUT_DIM; ++j) m = fmaxf(m, acc[j]);
    float ssum = 0.f;
#pragma unroll
    for (int j = 0; j < OUT_DIM; ++j) ssum += expf(acc[j] - m);
    float lse = m + logf(ssum);
    float* o = out + (size_t)n * OUT_DIM;
#pragma unroll
    for (int j = 0; j < OUT_DIM; ++j) o[j] = acc[j] - lse;
}

// ----------------------------------------------------------------- launcher
extern "C" void kernel_launch(void* const* d_in, const int* in_sizes, int n_in,
                              void* d_out, int out_size, void* d_ws, size_t ws_size,
                              hipStream_t stream) {
    const float* h    = (const float*)d_in[0];
    const int*   src  = (const int*)d_in[1];
    const int*   dst  = (const int*)d_in[2];
    const float* t1_w = (const float*)d_in[3];
    const float* t1_b = (const float*)d_in[4];
    const float* gw1  = (const float*)d_in[5];
    const float* gb1  = (const float*)d_in[6];
    const float* gw2  = (const float*)d_in[7];
    const float* gb2  = (const float*)d_in[8];
    const float* t2_w = (const float*)d_in[9];
    const float* t2_b = (const float*)d_in[10];
    float* out = (float*)d_out;

    const int N = in_sizes[0] / IN_DIM;
    const int E = in_sizes[1];
    const int NB = (N + SCAN_BLK - 1) / SCAN_BLK;

    // workspace layout (N*4 bytes is 16B-aligned for N=50000)
    float* ws   = (float*)d_ws;
    float* raw  = ws;                          // N*64
    float* xA   = raw + (size_t)N * HID;       // N*64
    float* xB   = xA + (size_t)N * HID;        // N*64
    float* dinv = xB + (size_t)N * HID;        // N
    float* gpa1 = dinv + N;                    // N
    float* gpb1 = gpa1 + N;                    // N
    float* gpa2 = gpb1 + N;                    // N
    float* gpb2 = gpa2 + N;                    // N
    short* wpre = (short*)(gpb2 + N);          // HID*IN_DIM bf16 (32KB)
    int* deg    = (int*)(wpre + HID * IN_DIM); // N
    int* incl   = deg + N;                     // N
    int* rowp   = incl + N;                    // N+1
    int* cursor = rowp + N + 1;                // N
    int* bsum   = cursor + N;                  // NB
    int* boff   = bsum + NB;                   // NB
    int* ssrc   = boff + NB;                   // E

    const int TB = 256;
    hipMemsetAsync(deg, 0, (size_t)N * sizeof(int), stream);
    k_deg<<<(E + TB - 1) / TB, TB, 0, stream>>>(dst, deg, E);
    k_dinv<<<NB, TB, 0, stream>>>(deg, dinv, N);
    k_scan_block<<<NB, TB, 0, stream>>>(deg, incl, bsum, N);
    k_scan_tops<<<1, TB, 0, stream>>>(bsum, boff, NB);
    k_scan_add<<<NB, TB, 0, stream>>>(incl, boff, deg, rowp, cursor, N);
    k_place<<<(E + TB - 1) / TB, TB, 0, stream>>>(src, dst, cursor, ssrc, E);

    k_wconv<<<(HID * IN_DIM + TB - 1) / TB, TB, 0, stream>>>(t1_w, wpre, HID * IN_DIM);

    // x0 = relu(h W1^T + b1), plus layer-1 gate projections
    k_gemm1<<<(N + 63) / 64, TB, 0, stream>>>(h, wpre, t1_b, gw1, raw, gpa1, gpb1, N);

    // layer 1: raw -> xA (epilogue computes layer-2 gate projections)
    k_gather<<<(N + 3) / 4, TB, 0, stream>>>(rowp, ssrc, gpa1, gpb1, dinv, gb1,
                                             raw, raw, xA, gw2, gpa2, gpb2, N);

    // layer 2: xA -> xB
    k_gather<<<(N + 3) / 4, TB, 0, stream>>>(rowp, ssrc, gpa2, gpb2, dinv, gb2,
                                             xA, raw, xB, nullptr, nullptr, nullptr, N);

    k_head<<<(N + TB - 1) / TB, TB, 0, stream>>>(xB, t2_w, t2_b, out, N);
}